// Round 7
// baseline (320.192 us; speedup 1.0000x reference)
//
#include <hip/hip_runtime.h>

// out[n,m] = -sum_d |x[n,d]-y[m,d]|  N=M=2048, D=128, fp32.  VALU-bound.
// R5 post-mortem: allocator targets 8 waves/SIMD (64 VGPR) and SPILLED
// acc (WRITE_SIZE +8.7MB scratch). Fix: size live set UNDER 64 VGPR
// instead of fighting the allocator. ROWS 16->8: yv[8](32)+acc[8](8)+
// temps ~= 52 < 64. Occupancy doubles to 8 waves/SIMD.
// x via uniform-address ds_read_b128 broadcast (in-order, conflict-free,
// ~1 bank cycle); y per-lane resident in VGPRs, chunked 32 floats.
// Block = 4 waves = 32 rows x 64 cols; grid 2048 = 8 blocks/CU (128KB LDS).

typedef float f4 __attribute__((ext_vector_type(4)));

#define DD 128
#define BR 32     // rows per block
#define ROWS 8    // rows per wave
#define NCH 4     // y-chunks of 32 floats

__launch_bounds__(256, 8)   // pin the 64-VGPR / 8-wave-per-EU operating point
__global__ void l1_dist_kernel(const float* __restrict__ X,
                               const float* __restrict__ Y,
                               float* __restrict__ out,
                               int N, int M) {
    __shared__ float xs[BR * DD];   // 16 KB

    const int tid = threadIdx.x;
    const int wave = tid >> 6;
    const int lane = tid & 63;
    const int brow = blockIdx.y * BR;
    const int bcol = blockIdx.x * 64;
    const int wrow = wave * ROWS;        // block-local row base for this wave
    const int m = bcol + lane;           // this lane's column

    // Stage x tile: 32 rows x 128 floats = 1024 f4; 256 threads -> 4 each.
#pragma unroll
    for (int k = 0; k < 4; ++k) {
        int idx = tid + k * 256;
        int r = idx >> 5, q = idx & 31;
        *(f4*)&xs[r * DD + (q << 2)] =
            *(const f4*)&X[(size_t)(brow + r) * DD + (q << 2)];
    }
    __syncthreads();

    float acc[ROWS];
#pragma unroll
    for (int r = 0; r < ROWS; ++r) acc[r] = 0.f;

#pragma unroll 1   // chunks sequential: live set stays ~52 VGPR
    for (int c = 0; c < NCH; ++c) {
        f4 yv[8];                         // 32 VGPR, this lane's y chunk
        const f4* yp = (const f4*)(Y + (size_t)m * DD + c * 32);
#pragma unroll
        for (int k = 0; k < 8; ++k) yv[k] = yp[k];

#pragma unroll
        for (int r = 0; r < ROWS; ++r) {
            const f4* xp = (const f4*)&xs[(wrow + r) * DD + c * 32]; // uniform
            float a0 = 0.f, a1 = 0.f, a2 = 0.f, a3 = 0.f;
#pragma unroll
            for (int k = 0; k < 8; ++k) {
                f4 xv = xp[k];            // ds_read_b128 broadcast
                a0 += __builtin_fabsf(xv.x - yv[k].x);
                a1 += __builtin_fabsf(xv.y - yv[k].y);
                a2 += __builtin_fabsf(xv.z - yv[k].z);
                a3 += __builtin_fabsf(xv.w - yv[k].w);
            }
            acc[r] += (a0 + a1) + (a2 + a3);
        }
    }

#pragma unroll
    for (int r = 0; r < ROWS; ++r)
        out[(size_t)(brow + wrow + r) * M + m] = -acc[r];  // 256B/wave store

}

extern "C" void kernel_launch(void* const* d_in, const int* in_sizes, int n_in,
                              void* d_out, int out_size, void* d_ws, size_t ws_size,
                              hipStream_t stream) {
    const float* x = (const float*)d_in[0];
    const float* y = (const float*)d_in[1];
    float* out = (float*)d_out;
    const int N = in_sizes[0] / DD;   // 2048
    const int M = in_sizes[1] / DD;   // 2048
    dim3 grid(M / 64, N / BR);        // (32, 64) = 2048 blocks
    l1_dist_kernel<<<grid, 256, 0, stream>>>(x, y, out, N, M);
}

// Round 8
// 48.346 us; speedup vs baseline: 6.6230x; 6.6230x over previous
//
#include <hip/hip_runtime.h>

// out[n,m] = -sum_d |x[n,d]-y[m,d]|  N=M=2048, D=128, fp32.  VALU-bound.
// R6 post-mortem: launch_bounds min-waves>=4 makes the allocator target a
// tiny VGPR budget and spill (R6: VGPR=32, 1.2GB scratch traffic). Only
// (256,2) ever protected register residency (R1: VGPR=128, no remat).
// R7 = proven pieces combined:
//  - y chunk (32 floats = 8 f4 = 32 VGPR) resident under (256,2); asm
//    keep-alives make the loads non-rematerializable.
//  - x via uniform-address ds_read_b128 BROADCAST from an 8KB LDS tile
//    (same addr across lanes = HW broadcast, 0 conflicts, in-order).
//  - block = 16 rows x 256 cols (4 waves share x tile); grid 1024 = 4/CU.
// Useful VALU = 32.8k cyc/SIMD => ~14us floor; predict 17-23us.

typedef float f4 __attribute__((ext_vector_type(4)));

#define DD 128
#define BR 16     // rows per block (= rows per wave; waves differ in cols)
#define NCH 4     // d-chunks of 32 floats

__launch_bounds__(256, 2)
__global__ void l1_dist_kernel(const float* __restrict__ X,
                               const float* __restrict__ Y,
                               float* __restrict__ out,
                               int N, int M) {
    __shared__ f4 xs[BR * 32];   // 16 rows x 32 f4 = 8 KB

    const int tid  = threadIdx.x;
    const int wave = tid >> 6;
    const int lane = tid & 63;
    const int brow = blockIdx.y * BR;
    const int bcol = blockIdx.x * 256;
    const int m    = bcol + wave * 64 + lane;   // this lane's column

    // Stage x tile: 512 f4, 256 threads -> 2 each. Coalesced 16B/thread.
#pragma unroll
    for (int k = 0; k < 2; ++k) {
        int idx = tid + k * 256;
        int r = idx >> 5, q = idx & 31;
        xs[r * 32 + q] = *(const f4*)&X[(size_t)(brow + r) * DD + (q << 2)];
    }
    __syncthreads();

    float acc[BR];
#pragma unroll
    for (int r = 0; r < BR; ++r) acc[r] = 0.f;

#pragma unroll 1   // chunks strictly sequential: keeps live set ~90 VGPR
    for (int c = 0; c < NCH; ++c) {
        // This lane's y chunk: one 128B line, 8 f4 loads, L2/L1-hot.
        f4 yv[8];
        const f4* yp = (const f4*)(Y + (size_t)m * DD + c * 32);
#pragma unroll
        for (int k = 0; k < 8; ++k) {
            yv[k] = yp[k];
            // pin in VGPRs: redefine through asm so the load can't be
            // rematerialized inside the row loop (R4/R5 failure mode)
            asm volatile("" : "+v"(yv[k]));
        }

#pragma unroll 2   // 2 rows in flight: DS latency overlap, modest pressure
        for (int r = 0; r < BR; ++r) {
            const f4* xp = &xs[r * 32 + c * 8];   // wave-uniform address
            float a0 = 0.f, a1 = 0.f, a2 = 0.f, a3 = 0.f;
#pragma unroll
            for (int k = 0; k < 8; ++k) {
                f4 xv = xp[k];                    // ds_read_b128 broadcast
                a0 += __builtin_fabsf(xv.x - yv[k].x);
                a1 += __builtin_fabsf(xv.y - yv[k].y);
                a2 += __builtin_fabsf(xv.z - yv[k].z);
                a3 += __builtin_fabsf(xv.w - yv[k].w);
            }
            acc[r] += (a0 + a1) + (a2 + a3);
        }
    }

#pragma unroll
    for (int r = 0; r < BR; ++r)
        out[(size_t)(brow + r) * M + m] = -acc[r];   // 256B/wave stores

}

extern "C" void kernel_launch(void* const* d_in, const int* in_sizes, int n_in,
                              void* d_out, int out_size, void* d_ws, size_t ws_size,
                              hipStream_t stream) {
    const float* x = (const float*)d_in[0];
    const float* y = (const float*)d_in[1];
    float* out = (float*)d_out;
    const int N = in_sizes[0] / DD;   // 2048
    const int M = in_sizes[1] / DD;   // 2048
    dim3 grid(M / 256, N / BR);       // (8, 128) = 1024 blocks = 4/CU
    l1_dist_kernel<<<grid, 256, 0, stream>>>(x, y, out, N, M);
}